// Round 1
// baseline (10401.845 us; speedup 1.0000x reference)
//
#include <hip/hip_runtime.h>
#include <math.h>

// Problem constants (from reference): B=16, T=8, C=3, H=W=14, HID=32, IND=16, N=3
// hidden[n]: (16,32,14,14) = 100352 floats
// bu matmul: (16,K) @ (3136,K)^T ; td matmul: (16,6272) @ (9408,6272)^T

// -------------------------------------------------------------------------
// Skinny matmul: out[b,n] = dot(in[b, :K], W[n, :K]) + bias[n], b in [0,16)
// 256 threads = 4 waves; 4 output rows per wave (16 rows/block).
// Input rows staged in LDS in 512-column chunks; weights streamed float4.
// -------------------------------------------------------------------------
template<bool RELU_IN, bool RELU_OUT>
__global__ __launch_bounds__(256) void matmul_tn(
    const float* __restrict__ in, int in_stride,
    const float* __restrict__ W, const float* __restrict__ bias,
    float* __restrict__ out, int N, int K)
{
    __shared__ float lds[16 * 512];   // 32 KB
    const int tid  = threadIdx.x;
    const int wave = tid >> 6;
    const int lane = tid & 63;
    const int n0   = blockIdx.x * 16 + wave * 4;

    bool rv[4];
    const float* wr[4];
#pragma unroll
    for (int r = 0; r < 4; ++r) {
        rv[r] = (n0 + r) < N;
        wr[r] = W + (size_t)(n0 + r) * K;
    }

    float acc[4][16];
#pragma unroll
    for (int r = 0; r < 4; ++r)
#pragma unroll
        for (int b = 0; b < 16; ++b) acc[r][b] = 0.f;

    for (int k0 = 0; k0 < K; k0 += 512) {
        const int len = min(512, K - k0);
        __syncthreads();
        for (int i = tid; i < 16 * 512; i += 256) {
            const int b = i >> 9, kk = i & 511;
            if (kk < len) {
                float v = in[b * in_stride + k0 + kk];
                if (RELU_IN) v = fmaxf(v, 0.f);
                lds[i] = v;
            }
        }
        __syncthreads();
        for (int kk = lane * 4; kk < len; kk += 256) {
            float4 w[4];
#pragma unroll
            for (int r = 0; r < 4; ++r)
                w[r] = rv[r] ? *(const float4*)(wr[r] + k0 + kk)
                             : make_float4(0.f, 0.f, 0.f, 0.f);
#pragma unroll
            for (int b = 0; b < 16; ++b) {
                const float4 v = *(const float4*)(&lds[(b << 9) + kk]);
#pragma unroll
                for (int r = 0; r < 4; ++r) {
                    acc[r][b] += w[r].x * v.x + w[r].y * v.y +
                                 w[r].z * v.z + w[r].w * v.w;
                }
            }
        }
    }

#pragma unroll
    for (int r = 0; r < 4; ++r) {
        const float brv = rv[r] ? bias[n0 + r] : 0.f;
#pragma unroll
        for (int b = 0; b < 16; ++b) {
            float v = acc[r][b];
#pragma unroll
            for (int off = 32; off > 0; off >>= 1)
                v += __shfl_down(v, off, 64);
            if (lane == 0 && rv[r]) {
                v += brv;
                if (RELU_OUT) v = fmaxf(v, 0.f);
                out[b * N + (n0 + r)] = v;
            }
        }
    }
}

// -------------------------------------------------------------------------
// MaxPool 3x3, stride 1, pad 1, on (16,32,14,14) -> flat (16,6272)
// -------------------------------------------------------------------------
__global__ __launch_bounds__(256) void maxpool3_k(const float* __restrict__ h,
                                                  float* __restrict__ out)
{
    int i = blockIdx.x * 256 + threadIdx.x;
    if (i >= 16 * 32 * 196) return;
    int p = i % 196;
    int y = p / 14, x = p - y * 14;
    const float* base = h + (i - p);
    int y0 = max(y - 1, 0), y1 = min(y + 1, 13);
    int x0 = max(x - 1, 0), x1 = min(x + 1, 13);
    float m = -INFINITY;
    for (int yy = y0; yy <= y1; ++yy)
        for (int xc = x0; xc <= x1; ++xc)
            m = fmaxf(m, base[yy * 14 + xc]);
    out[i] = m;
}

// -------------------------------------------------------------------------
// Gate conv: gates = sigmoid(conv3x3(cat[bu(16ch), h(32ch)] (+ td), Wg, bg))
// o in [0,32): rh = sigmoid*h ; o in [32,64): z = sigmoid
// -------------------------------------------------------------------------
template<bool HAS_TD>
__global__ __launch_bounds__(256) void gate_conv(
    const float* __restrict__ bu, const float* __restrict__ h,
    const float* __restrict__ td,
    const float* __restrict__ Wg, const float* __restrict__ bg,
    float* __restrict__ rh, float* __restrict__ z)
{
    int i = blockIdx.x * 256 + threadIdx.x;
    if (i >= 16 * 64 * 196) return;
    int p = i % 196;
    int rest = i / 196;
    int o = rest & 63;
    int b = rest >> 6;
    int y = p / 14, x = p - y * 14;
    int ky0 = (y == 0) ? 1 : 0, ky1 = (y == 13) ? 2 : 3;
    int kx0 = (x == 0) ? 1 : 0, kx1 = (x == 13) ? 2 : 3;

    float acc = bg[o];
    const float* wb  = Wg + o * 432;           // 48*9
    const float* bub = bu + b * 3136;          // 16*196
    const float* hb  = h  + b * 6272;          // 32*196
    const float* tdb = HAS_TD ? td + b * 9408 : nullptr;  // 48*196

    for (int ci = 0; ci < 48; ++ci) {
        const float* src = (ci < 16) ? (bub + ci * 196) : (hb + (ci - 16) * 196);
        const float* w   = wb + ci * 9;
        const float* tp  = HAS_TD ? (tdb + ci * 196) : nullptr;
        for (int ky = ky0; ky < ky1; ++ky) {
            int q = p + (ky - 1) * 14 - 1;
            for (int kx = kx0; kx < kx1; ++kx) {
                float v = src[q + kx];
                if (HAS_TD) v += tp[q + kx];
                acc += v * w[ky * 3 + kx];
            }
        }
    }
    float g = 1.f / (1.f + expf(-acc));
    if (o < 32) {
        int idx = (b * 32 + o) * 196 + p;
        rh[idx] = g * h[idx];
    } else {
        int idx = (b * 32 + (o - 32)) * 196 + p;
        z[idx] = g;
    }
}

// -------------------------------------------------------------------------
// Candidate conv + GRU update:
// cand = tanh(conv3x3(cat[bu(16ch), rh(32ch)], Wc, bc)); h = (1-z)*h + z*cand
// -------------------------------------------------------------------------
__global__ __launch_bounds__(256) void cand_conv(
    const float* __restrict__ bu, const float* __restrict__ rh,
    const float* __restrict__ z,
    const float* __restrict__ Wc, const float* __restrict__ bc,
    float* __restrict__ h)
{
    int i = blockIdx.x * 256 + threadIdx.x;
    if (i >= 16 * 32 * 196) return;
    int p = i % 196;
    int rest = i / 196;
    int o = rest & 31;
    int b = rest >> 5;
    int y = p / 14, x = p - y * 14;
    int ky0 = (y == 0) ? 1 : 0, ky1 = (y == 13) ? 2 : 3;
    int kx0 = (x == 0) ? 1 : 0, kx1 = (x == 13) ? 2 : 3;

    float acc = bc[o];
    const float* wb  = Wc + o * 432;
    const float* bub = bu + b * 3136;
    const float* rhb = rh + b * 6272;

    for (int ci = 0; ci < 48; ++ci) {
        const float* src = (ci < 16) ? (bub + ci * 196) : (rhb + (ci - 16) * 196);
        const float* w   = wb + ci * 9;
        for (int ky = ky0; ky < ky1; ++ky) {
            int q = p + (ky - 1) * 14 - 1;
            for (int kx = kx0; kx < kx1; ++kx)
                acc += src[q + kx] * w[ky * 3 + kx];
        }
    }
    float cand = tanhf(acc);
    int idx = (b * 32 + o) * 196 + p;
    float zv = z[idx];
    h[idx] = (1.f - zv) * h[idx] + zv * cand;
}

// -------------------------------------------------------------------------
extern "C" void kernel_launch(void* const* d_in, const int* in_sizes, int n_in,
                              void* d_out, int out_size, void* d_ws, size_t ws_size,
                              hipStream_t stream)
{
    (void)in_sizes; (void)n_in; (void)out_size; (void)ws_size;

    const float* x     = (const float*)d_in[0];
    const float* Wg    = (const float*)d_in[1];
    const float* bg    = (const float*)d_in[2];
    const float* Wc    = (const float*)d_in[3];
    const float* bc    = (const float*)d_in[4];
    const float* bu_w[3] = {(const float*)d_in[5], (const float*)d_in[7], (const float*)d_in[9]};
    const float* bu_b[3] = {(const float*)d_in[6], (const float*)d_in[8], (const float*)d_in[10]};
    const float* td_w[2] = {(const float*)d_in[11], (const float*)d_in[13]};
    const float* td_b[2] = {(const float*)d_in[12], (const float*)d_in[14]};
    const float* fc1_w = (const float*)d_in[15];
    const float* fc1_b = (const float*)d_in[16];
    const float* fc2_w = (const float*)d_in[17];
    const float* fc2_b = (const float*)d_in[18];
    float* out = (float*)d_out;

    float* ws      = (float*)d_ws;
    float* hid0    = ws;                    // 100352 each
    float* hid1    = hid0 + 100352;
    float* hid2    = hid1 + 100352;
    float* bu_buf  = hid2 + 100352;         // 16*3136
    float* td_buf  = bu_buf + 50176;        // 16*9408
    float* mp_buf  = td_buf + 150528;       // 16*6272
    float* mp2_buf = mp_buf + 100352;       // 16*6272
    float* rh_buf  = mp2_buf + 100352;      // 16*32*196
    float* z_buf   = rh_buf + 100352;       // 16*32*196
    float* p1_buf  = z_buf + 100352;        // 16*100

    float* hids[3] = {hid0, hid1, hid2};

    // hidden states start at zero every call (ws is re-poisoned by harness)
    hipMemsetAsync(ws, 0, 3 * 100352 * sizeof(float), stream);

    #define MM(inp, stride, Wp, bp, op, N, K) \
        matmul_tn<false,false><<<dim3((unsigned)(((N) + 15) / 16)), dim3(256), 0, stream>>>( \
            (inp), (stride), (Wp), (bp), (op), (N), (K))

    for (int t = 0; t < 10; ++t) {          // T + N - 1 = 10
        // ---- node 0 (runs while input remains) ----
        if (t < 8) {
            MM(x + t * 588, 8 * 588, bu_w[0], bu_b[0], bu_buf, 3136, 588);
            const bool has_td = (t >= 2);   // reads hid1 PRE-update (node0 first)
            if (has_td) {
                maxpool3_k<<<392, 256, 0, stream>>>(hid1, mp2_buf);
                MM(mp2_buf, 6272, td_w[0], td_b[0], td_buf, 9408, 6272);
                gate_conv<true><<<784, 256, 0, stream>>>(bu_buf, hid0, td_buf, Wg, bg, rh_buf, z_buf);
            } else {
                gate_conv<false><<<784, 256, 0, stream>>>(bu_buf, hid0, nullptr, Wg, bg, rh_buf, z_buf);
            }
            cand_conv<<<392, 256, 0, stream>>>(bu_buf, rh_buf, z_buf, Wc, bc, hid0);
        }
        // ---- node 1 (reads hid0 POST-update this t, hid2 PRE-update) ----
        if (t >= 1) {
            maxpool3_k<<<392, 256, 0, stream>>>(hid0, mp_buf);
            MM(mp_buf, 6272, bu_w[1], bu_b[1], bu_buf, 3136, 6272);
            const bool has_td = (t >= 2);
            const float* wg1 = Wg + 27648;  // 64*48*9
            const float* bg1 = bg + 64;
            if (has_td) {
                maxpool3_k<<<392, 256, 0, stream>>>(hid2, mp2_buf);
                MM(mp2_buf, 6272, td_w[1], td_b[1], td_buf, 9408, 6272);
                gate_conv<true><<<784, 256, 0, stream>>>(bu_buf, hid1, td_buf, wg1, bg1, rh_buf, z_buf);
            } else {
                gate_conv<false><<<784, 256, 0, stream>>>(bu_buf, hid1, nullptr, wg1, bg1, rh_buf, z_buf);
            }
            cand_conv<<<392, 256, 0, stream>>>(bu_buf, rh_buf, z_buf, Wc + 13824, bc + 32, hid1);
        }
        // ---- node 2 (reads hid1 POST-update this t; no td) ----
        if (t >= 1) {
            maxpool3_k<<<392, 256, 0, stream>>>(hid1, mp_buf);
            MM(mp_buf, 6272, bu_w[2], bu_b[2], bu_buf, 3136, 6272);
            gate_conv<false><<<784, 256, 0, stream>>>(bu_buf, hid2, nullptr,
                                                      Wg + 2 * 27648, bg + 128, rh_buf, z_buf);
            cand_conv<<<392, 256, 0, stream>>>(bu_buf, rh_buf, z_buf, Wc + 2 * 13824, bc + 64, hid2);
        }
    }

    // ---- head: relu(hid2) @ fc1^T -> relu -> @ fc2^T ----
    matmul_tn<true, true><<<dim3(7), dim3(256), 0, stream>>>(hid2, 6272, fc1_w, fc1_b, p1_buf, 100, 6272);
    matmul_tn<false, false><<<dim3(1), dim3(256), 0, stream>>>(p1_buf, 100, fc2_w, fc2_b, out, 10, 100);

    #undef MM
    (void)hids;
}